// Round 12
// baseline (65.965 us; speedup 1.0000x reference)
//
#include <hip/hip_runtime.h>
#include <hip/hip_bf16.h>

// GraphAttentionLayer: bs=8, N=2048, Fin=128, Fout=64, fp32.
// h_prime[b,n,:] = sum_m softmax_m(LeakyReLU(e1[n]+e2[m]+ab)) * adj[b,n,m] * Wh[b,m,:]
// Identity: exp(LeakyReLU(y)) = max(exp(y), exp(0.1*y))
//   => pa[n,m] = max(c1[n]*E1[m], c2[n]*E2[m]).
// R12: 2 kernels. wh_kernel = GEMM + e1/E1/E2 + fused bf16-fragment pack
// (no fp32 Wh array at all). attn_mfma = fused adj stream (nontemporal) +
// dense-MFMA numerator + dense denom.

#define ALPHA 0.1f
constexpr int B    = 8;
constexpr int N    = 2048;
constexpr int FIN  = 128;
constexpr int FOUT = 64;

typedef __bf16 bf16x8 __attribute__((ext_vector_type(8)));
typedef float  f32x4  __attribute__((ext_vector_type(4)));
typedef float  f4     __attribute__((ext_vector_type(4)));

// ---------------- Kernel 1: GEMM + side outputs + fused pack ---------------
// 16 rows per block. Whb fragment unit = bf16x8 per (b, mc=m/32, ct=o/16,
// ln=kg*16+col): element j = Wh[mc*32+kg*8+j][ct*16+col]. A 16-row block
// covers kg in {kg_base, kg_base+1} of chunk mc = n0/32.
__global__ __launch_bounds__(256) void wh_kernel(
    const float* __restrict__ h, const float* __restrict__ W,
    const float* __restrict__ bias, const float* __restrict__ a_w,
    const float* __restrict__ a_b,
    float* __restrict__ e1, float* __restrict__ E1, float* __restrict__ E2,
    unsigned short* __restrict__ Whb)
{
    __shared__ __align__(16) float Wl4[FIN * FOUT];   // 32 KB, packed (k4,o,kj)
    __shared__ __align__(16) float hl[16 * FIN];      // 8 KB
    __shared__ __align__(16) float sAcc[16][64];      // 4 KB

    const int tid = threadIdx.x;
    const int blk = blockIdx.x;           // 0..1023
    const int b   = blk >> 7;
    const int n0  = (blk & 127) * 16;

    for (int i = tid; i < FIN * FOUT / 4; i += 256) {
        float4 wv = ((const float4*)W)[i];     // W[k][o4..o4+3]
        int k  = i >> 4;
        int o4 = (i & 15) * 4;
        int k4 = k >> 2, kj = k & 3;
        Wl4[(k4 * 64 + o4 + 0) * 4 + kj] = wv.x;
        Wl4[(k4 * 64 + o4 + 1) * 4 + kj] = wv.y;
        Wl4[(k4 * 64 + o4 + 2) * 4 + kj] = wv.z;
        Wl4[(k4 * 64 + o4 + 3) * 4 + kj] = wv.w;
    }
    const float* hb = h + (size_t)(b * N + n0) * FIN;
    for (int i = tid; i < 16 * FIN / 4; i += 256)
        ((float4*)hl)[i] = ((const float4*)hb)[i];
    __syncthreads();

    const int w  = tid >> 6;
    const int o  = tid & 63;
    const int r0 = w * 4;

    float acc[4];
    float bo_ = bias[o];
    #pragma unroll
    for (int rr = 0; rr < 4; ++rr) acc[rr] = bo_;

    #pragma unroll 8
    for (int k4 = 0; k4 < FIN / 4; ++k4) {
        float4 wv = ((const float4*)Wl4)[k4 * 64 + o];
        #pragma unroll
        for (int rr = 0; rr < 4; ++rr) {
            float4 hv = ((const float4*)hl)[(r0 + rr) * 32 + k4];
            acc[rr] = fmaf(hv.x, wv.x, acc[rr]);
            acc[rr] = fmaf(hv.y, wv.y, acc[rr]);
            acc[rr] = fmaf(hv.z, wv.z, acc[rr]);
            acc[rr] = fmaf(hv.w, wv.w, acc[rr]);
        }
    }

    const float a1 = a_w[o], a2 = a_w[FOUT + o];
    const float ab = a_b[0];
    #pragma unroll
    for (int rr = 0; rr < 4; ++rr) {
        const int n = n0 + r0 + rr;
        sAcc[r0 + rr][o] = acc[rr];
        float v1 = acc[rr] * a1;
        float v2 = acc[rr] * a2;
        #pragma unroll
        for (int off = 32; off > 0; off >>= 1) {
            v1 += __shfl_xor(v1, off, 64);
            v2 += __shfl_xor(v2, off, 64);
        }
        if (o == 0) {
            e1[b * N + n] = v1 + ab;          // rowbase, a_b folded in
            E1[b * N + n] = __expf(v2);
            E2[b * N + n] = __expf(ALPHA * v2);
        }
    }
    __syncthreads();

    // ---- fused pack: sAcc -> bf16 B-fragment units ------------------------
    if (tid < 128) {
        const int ct  = tid >> 5;         // 0..3 col-tile
        const int kgl = (tid >> 4) & 1;   // 0..1 local k-group
        const int col = tid & 15;
        const int mc      = n0 >> 5;
        const int kg_base = (n0 & 16) ? 2 : 0;
        const int kg      = kg_base + kgl;

        unsigned short us[8];
        #pragma unroll
        for (int j = 0; j < 8; ++j) {
            unsigned int u = __float_as_uint(sAcc[kgl * 8 + j][ct * 16 + col]);
            u += 0x7FFFu + ((u >> 16) & 1u);           // RNE to bf16
            us[j] = (unsigned short)(u >> 16);
        }
        int4 pk;
        pk.x = (int)(us[0] | ((unsigned)us[1] << 16));
        pk.y = (int)(us[2] | ((unsigned)us[3] << 16));
        pk.z = (int)(us[4] | ((unsigned)us[5] << 16));
        pk.w = (int)(us[6] | ((unsigned)us[7] << 16));
        ((int4*)Whb)[(((size_t)b * 64 + mc) * 4 + ct) * 64 + kg * 16 + col] = pk;
    }
}

// ---------------- Kernel 2: dense attention via MFMA -----------------------
struct Frag {
    f4 a0, a1;
    float4 x0, x1, y0, y1;
    bf16x8 b0, b1, b2, b3;
};

__device__ __forceinline__ void load_step(
    Frag& f, const float* adjr, const float* E1b, const float* E2b,
    const bf16x8* BfragB, int w, int t, int kg, int lane)
{
    const int mo = w * 512 + t * 32 + kg * 8;
    f.a0 = __builtin_nontemporal_load((const f4*)(adjr + mo));      // single-use
    f.a1 = __builtin_nontemporal_load((const f4*)(adjr + mo + 4));
    f.x0 = *(const float4*)(E1b + mo);
    f.x1 = *(const float4*)(E1b + mo + 4);
    f.y0 = *(const float4*)(E2b + mo);
    f.y1 = *(const float4*)(E2b + mo + 4);
    const bf16x8* bp = BfragB + (size_t)(w * 16 + t) * 256 + lane;
    f.b0 = bp[0];
    f.b1 = bp[64];
    f.b2 = bp[128];
    f.b3 = bp[192];
}

__device__ __forceinline__ void compute_step(
    const Frag& f, float c1, float c2, float& denom,
    f32x4& A0, f32x4& A1, f32x4& A2, f32x4& A3)
{
    float p[8], q[8];
    p[0] = fmaxf(c1 * f.x0.x, c2 * f.y0.x); q[0] = p[0] * f.a0.x;
    p[1] = fmaxf(c1 * f.x0.y, c2 * f.y0.y); q[1] = p[1] * f.a0.y;
    p[2] = fmaxf(c1 * f.x0.z, c2 * f.y0.z); q[2] = p[2] * f.a0.z;
    p[3] = fmaxf(c1 * f.x0.w, c2 * f.y0.w); q[3] = p[3] * f.a0.w;
    p[4] = fmaxf(c1 * f.x1.x, c2 * f.y1.x); q[4] = p[4] * f.a1.x;
    p[5] = fmaxf(c1 * f.x1.y, c2 * f.y1.y); q[5] = p[5] * f.a1.y;
    p[6] = fmaxf(c1 * f.x1.z, c2 * f.y1.z); q[6] = p[6] * f.a1.z;
    p[7] = fmaxf(c1 * f.x1.w, c2 * f.y1.w); q[7] = p[7] * f.a1.w;
    denom += ((p[0] + p[1]) + (p[2] + p[3])) + ((p[4] + p[5]) + (p[6] + p[7]));

    bf16x8 af;
    af[0] = (__bf16)q[0]; af[1] = (__bf16)q[1];
    af[2] = (__bf16)q[2]; af[3] = (__bf16)q[3];
    af[4] = (__bf16)q[4]; af[5] = (__bf16)q[5];
    af[6] = (__bf16)q[6]; af[7] = (__bf16)q[7];

    A0 = __builtin_amdgcn_mfma_f32_16x16x32_bf16(af, f.b0, A0, 0, 0, 0);
    A1 = __builtin_amdgcn_mfma_f32_16x16x32_bf16(af, f.b1, A1, 0, 0, 0);
    A2 = __builtin_amdgcn_mfma_f32_16x16x32_bf16(af, f.b2, A2, 0, 0, 0);
    A3 = __builtin_amdgcn_mfma_f32_16x16x32_bf16(af, f.b3, A3, 0, 0, 0);
}

__global__ __launch_bounds__(256) void attn_mfma(
    const float* __restrict__ adj, const unsigned short* __restrict__ Whb,
    const float* __restrict__ e1, const float* __restrict__ E1,
    const float* __restrict__ E2, float* __restrict__ out)
{
    __shared__ float accs[4][16][66];   // [wave][crow][col], stride 66 anti-conflict
    __shared__ float dens[4][16];

    const int tid  = threadIdx.x;
    int blkr = blockIdx.x;
    const int blk = (blkr & 7) * 128 + (blkr >> 3);   // XCD swizzle: one batch/XCD
    const int b   = blk >> 7;
    const int n0  = (blk & 127) * 16;

    const int w      = tid >> 6;
    const int lane   = tid & 63;
    const int lane15 = lane & 15;
    const int kg     = lane >> 4;

    const int n_row = n0 + lane15;      // this lane's A-operand row
    const float rowbase = e1[b * N + n_row];
    const float c1 = __expf(rowbase);
    const float c2 = __expf(ALPHA * rowbase);

    const float* adjr  = adj + ((size_t)b * N + n_row) * N;
    const float* E1b   = E1 + b * N;
    const float* E2b   = E2 + b * N;
    const bf16x8* BfragB = (const bf16x8*)Whb + (size_t)b * 64 * 256;

    f32x4 A0 = {0.f, 0.f, 0.f, 0.f}, A1 = A0, A2 = A0, A3 = A0;
    float denom = 0.f;

    Frag fc, fn;
    load_step(fc, adjr, E1b, E2b, BfragB, w, 0, kg, lane);
    #pragma unroll
    for (int t = 0; t < 16; ++t) {
        if (t < 15)
            load_step(fn, adjr, E1b, E2b, BfragB, w, t + 1, kg, lane);
        compute_step(fc, c1, c2, denom, A0, A1, A2, A3);
        if (t < 15)
            fc = fn;
    }

    // row-denominator: lanes {r, r+16, r+32, r+48} hold row r partials
    denom += __shfl_xor(denom, 16, 64);
    denom += __shfl_xor(denom, 32, 64);
    if (lane < 16) dens[w][lane] = denom;

    // C-frag: col = lane&15, row = kg*4 + reg  (m89-verified layout)
    #pragma unroll
    for (int reg = 0; reg < 4; ++reg) {
        const int crow = kg * 4 + reg;
        accs[w][crow][ 0 + lane15] = A0[reg];
        accs[w][crow][16 + lane15] = A1[reg];
        accs[w][crow][32 + lane15] = A2[reg];
        accs[w][crow][48 + lane15] = A3[reg];
    }
    __syncthreads();

    // combine the 4 m-quarters and normalize
    const int col = tid & 63;
    const int rq  = tid >> 6;
    #pragma unroll
    for (int i = 0; i < 4; ++i) {
        const int r = rq * 4 + i;
        float s = (accs[0][r][col] + accs[1][r][col])
                + (accs[2][r][col] + accs[3][r][col]);
        float d = (dens[0][r] + dens[1][r]) + (dens[2][r] + dens[3][r]);
        out[((size_t)b * N + n0 + r) * FOUT + col] = s / d;
    }
}

extern "C" void kernel_launch(void* const* d_in, const int* in_sizes, int n_in,
                              void* d_out, int out_size, void* d_ws, size_t ws_size,
                              hipStream_t stream) {
    const float* h   = (const float*)d_in[0];
    const float* adj = (const float*)d_in[1];
    const float* W   = (const float*)d_in[2];
    const float* bv  = (const float*)d_in[3];
    const float* a_w = (const float*)d_in[4];
    const float* a_b = (const float*)d_in[5];
    float* out = (float*)d_out;

    float* e1 = (float*)d_ws;                    // B*N floats
    float* E1 = e1 + (size_t)B * N;              // B*N
    float* E2 = E1 + (size_t)B * N;              // B*N
    unsigned short* Whb = (unsigned short*)(E2 + (size_t)B * N);   // 2 MB bf16 frags

    wh_kernel<<<B * N / 16, 256, 0, stream>>>(h, W, bv, a_w, a_b, e1, E1, E2, Whb);
    attn_mfma<<<B * N / 16, 256, 0, stream>>>(adj, Whb, e1, E1, E2, out);
}

// Round 13
// 52.391 us; speedup vs baseline: 1.2591x; 1.2591x over previous
//
#include <hip/hip_runtime.h>
#include <hip/hip_bf16.h>

// GraphAttentionLayer: bs=8, N=2048, Fin=128, Fout=64, fp32.
// h_prime[b,n,:] = sum_m softmax_m(LeakyReLU(e1[n]+e2[m]+ab)) * adj[b,n,m] * Wh[b,m,:]
// Identity: exp(LeakyReLU(y)) = max(exp(y), exp(0.1*y))
//   => pa[n,m] = max(c1[n]*E1[m], c2[n]*E2[m]).
// R13 = R12 minus nontemporal loads (single-variable revert): 2 kernels,
// fused bf16-fragment pack in wh_kernel, plain adj loads in attn_mfma.

#define ALPHA 0.1f
constexpr int B    = 8;
constexpr int N    = 2048;
constexpr int FIN  = 128;
constexpr int FOUT = 64;

typedef __bf16 bf16x8 __attribute__((ext_vector_type(8)));
typedef float  f32x4  __attribute__((ext_vector_type(4)));

// ---------------- Kernel 1: GEMM + side outputs + fused pack ---------------
// 16 rows per block. Whb fragment unit = bf16x8 per (b, mc=m/32, ct=o/16,
// ln=kg*16+col): element j = Wh[mc*32+kg*8+j][ct*16+col]. A 16-row block
// covers kg in {kg_base, kg_base+1} of chunk mc = n0/32.
__global__ __launch_bounds__(256) void wh_kernel(
    const float* __restrict__ h, const float* __restrict__ W,
    const float* __restrict__ bias, const float* __restrict__ a_w,
    const float* __restrict__ a_b,
    float* __restrict__ e1, float* __restrict__ E1, float* __restrict__ E2,
    unsigned short* __restrict__ Whb)
{
    __shared__ __align__(16) float Wl4[FIN * FOUT];   // 32 KB, packed (k4,o,kj)
    __shared__ __align__(16) float hl[16 * FIN];      // 8 KB
    __shared__ __align__(16) float sAcc[16][64];      // 4 KB

    const int tid = threadIdx.x;
    const int blk = blockIdx.x;           // 0..1023
    const int b   = blk >> 7;
    const int n0  = (blk & 127) * 16;

    for (int i = tid; i < FIN * FOUT / 4; i += 256) {
        float4 wv = ((const float4*)W)[i];     // W[k][o4..o4+3]
        int k  = i >> 4;
        int o4 = (i & 15) * 4;
        int k4 = k >> 2, kj = k & 3;
        Wl4[(k4 * 64 + o4 + 0) * 4 + kj] = wv.x;
        Wl4[(k4 * 64 + o4 + 1) * 4 + kj] = wv.y;
        Wl4[(k4 * 64 + o4 + 2) * 4 + kj] = wv.z;
        Wl4[(k4 * 64 + o4 + 3) * 4 + kj] = wv.w;
    }
    const float* hb = h + (size_t)(b * N + n0) * FIN;
    for (int i = tid; i < 16 * FIN / 4; i += 256)
        ((float4*)hl)[i] = ((const float4*)hb)[i];
    __syncthreads();

    const int w  = tid >> 6;
    const int o  = tid & 63;
    const int r0 = w * 4;

    float acc[4];
    float bo_ = bias[o];
    #pragma unroll
    for (int rr = 0; rr < 4; ++rr) acc[rr] = bo_;

    #pragma unroll 8
    for (int k4 = 0; k4 < FIN / 4; ++k4) {
        float4 wv = ((const float4*)Wl4)[k4 * 64 + o];
        #pragma unroll
        for (int rr = 0; rr < 4; ++rr) {
            float4 hv = ((const float4*)hl)[(r0 + rr) * 32 + k4];
            acc[rr] = fmaf(hv.x, wv.x, acc[rr]);
            acc[rr] = fmaf(hv.y, wv.y, acc[rr]);
            acc[rr] = fmaf(hv.z, wv.z, acc[rr]);
            acc[rr] = fmaf(hv.w, wv.w, acc[rr]);
        }
    }

    const float a1 = a_w[o], a2 = a_w[FOUT + o];
    const float ab = a_b[0];
    #pragma unroll
    for (int rr = 0; rr < 4; ++rr) {
        const int n = n0 + r0 + rr;
        sAcc[r0 + rr][o] = acc[rr];
        float v1 = acc[rr] * a1;
        float v2 = acc[rr] * a2;
        #pragma unroll
        for (int off = 32; off > 0; off >>= 1) {
            v1 += __shfl_xor(v1, off, 64);
            v2 += __shfl_xor(v2, off, 64);
        }
        if (o == 0) {
            e1[b * N + n] = v1 + ab;          // rowbase, a_b folded in
            E1[b * N + n] = __expf(v2);
            E2[b * N + n] = __expf(ALPHA * v2);
        }
    }
    __syncthreads();

    // ---- fused pack: sAcc -> bf16 B-fragment units ------------------------
    if (tid < 128) {
        const int ct  = tid >> 5;         // 0..3 col-tile
        const int kgl = (tid >> 4) & 1;   // 0..1 local k-group
        const int col = tid & 15;
        const int mc      = n0 >> 5;
        const int kg_base = (n0 & 16) ? 2 : 0;
        const int kg      = kg_base + kgl;

        unsigned short us[8];
        #pragma unroll
        for (int j = 0; j < 8; ++j) {
            unsigned int u = __float_as_uint(sAcc[kgl * 8 + j][ct * 16 + col]);
            u += 0x7FFFu + ((u >> 16) & 1u);           // RNE to bf16
            us[j] = (unsigned short)(u >> 16);
        }
        int4 pk;
        pk.x = (int)(us[0] | ((unsigned)us[1] << 16));
        pk.y = (int)(us[2] | ((unsigned)us[3] << 16));
        pk.z = (int)(us[4] | ((unsigned)us[5] << 16));
        pk.w = (int)(us[6] | ((unsigned)us[7] << 16));
        ((int4*)Whb)[(((size_t)b * 64 + mc) * 4 + ct) * 64 + kg * 16 + col] = pk;
    }
}

// ---------------- Kernel 2: dense attention via MFMA -----------------------
struct Frag {
    float4 a0, a1;
    float4 x0, x1, y0, y1;
    bf16x8 b0, b1, b2, b3;
};

__device__ __forceinline__ void load_step(
    Frag& f, const float* adjr, const float* E1b, const float* E2b,
    const bf16x8* BfragB, int w, int t, int kg, int lane)
{
    const int mo = w * 512 + t * 32 + kg * 8;
    f.a0 = *(const float4*)(adjr + mo);
    f.a1 = *(const float4*)(adjr + mo + 4);
    f.x0 = *(const float4*)(E1b + mo);
    f.x1 = *(const float4*)(E1b + mo + 4);
    f.y0 = *(const float4*)(E2b + mo);
    f.y1 = *(const float4*)(E2b + mo + 4);
    const bf16x8* bp = BfragB + (size_t)(w * 16 + t) * 256 + lane;
    f.b0 = bp[0];
    f.b1 = bp[64];
    f.b2 = bp[128];
    f.b3 = bp[192];
}

__device__ __forceinline__ void compute_step(
    const Frag& f, float c1, float c2, float& denom,
    f32x4& A0, f32x4& A1, f32x4& A2, f32x4& A3)
{
    float p[8], q[8];
    p[0] = fmaxf(c1 * f.x0.x, c2 * f.y0.x); q[0] = p[0] * f.a0.x;
    p[1] = fmaxf(c1 * f.x0.y, c2 * f.y0.y); q[1] = p[1] * f.a0.y;
    p[2] = fmaxf(c1 * f.x0.z, c2 * f.y0.z); q[2] = p[2] * f.a0.z;
    p[3] = fmaxf(c1 * f.x0.w, c2 * f.y0.w); q[3] = p[3] * f.a0.w;
    p[4] = fmaxf(c1 * f.x1.x, c2 * f.y1.x); q[4] = p[4] * f.a1.x;
    p[5] = fmaxf(c1 * f.x1.y, c2 * f.y1.y); q[5] = p[5] * f.a1.y;
    p[6] = fmaxf(c1 * f.x1.z, c2 * f.y1.z); q[6] = p[6] * f.a1.z;
    p[7] = fmaxf(c1 * f.x1.w, c2 * f.y1.w); q[7] = p[7] * f.a1.w;
    denom += ((p[0] + p[1]) + (p[2] + p[3])) + ((p[4] + p[5]) + (p[6] + p[7]));

    bf16x8 af;
    af[0] = (__bf16)q[0]; af[1] = (__bf16)q[1];
    af[2] = (__bf16)q[2]; af[3] = (__bf16)q[3];
    af[4] = (__bf16)q[4]; af[5] = (__bf16)q[5];
    af[6] = (__bf16)q[6]; af[7] = (__bf16)q[7];

    A0 = __builtin_amdgcn_mfma_f32_16x16x32_bf16(af, f.b0, A0, 0, 0, 0);
    A1 = __builtin_amdgcn_mfma_f32_16x16x32_bf16(af, f.b1, A1, 0, 0, 0);
    A2 = __builtin_amdgcn_mfma_f32_16x16x32_bf16(af, f.b2, A2, 0, 0, 0);
    A3 = __builtin_amdgcn_mfma_f32_16x16x32_bf16(af, f.b3, A3, 0, 0, 0);
}

__global__ __launch_bounds__(256) void attn_mfma(
    const float* __restrict__ adj, const unsigned short* __restrict__ Whb,
    const float* __restrict__ e1, const float* __restrict__ E1,
    const float* __restrict__ E2, float* __restrict__ out)
{
    __shared__ float accs[4][16][66];   // [wave][crow][col], stride 66 anti-conflict
    __shared__ float dens[4][16];

    const int tid  = threadIdx.x;
    int blkr = blockIdx.x;
    const int blk = (blkr & 7) * 128 + (blkr >> 3);   // XCD swizzle: one batch/XCD
    const int b   = blk >> 7;
    const int n0  = (blk & 127) * 16;

    const int w      = tid >> 6;
    const int lane   = tid & 63;
    const int lane15 = lane & 15;
    const int kg     = lane >> 4;

    const int n_row = n0 + lane15;      // this lane's A-operand row
    const float rowbase = e1[b * N + n_row];
    const float c1 = __expf(rowbase);
    const float c2 = __expf(ALPHA * rowbase);

    const float* adjr  = adj + ((size_t)b * N + n_row) * N;
    const float* E1b   = E1 + b * N;
    const float* E2b   = E2 + b * N;
    const bf16x8* BfragB = (const bf16x8*)Whb + (size_t)b * 64 * 256;

    f32x4 A0 = {0.f, 0.f, 0.f, 0.f}, A1 = A0, A2 = A0, A3 = A0;
    float denom = 0.f;

    Frag fc, fn;
    load_step(fc, adjr, E1b, E2b, BfragB, w, 0, kg, lane);
    #pragma unroll
    for (int t = 0; t < 16; ++t) {
        if (t < 15)
            load_step(fn, adjr, E1b, E2b, BfragB, w, t + 1, kg, lane);
        compute_step(fc, c1, c2, denom, A0, A1, A2, A3);
        if (t < 15)
            fc = fn;
    }

    // row-denominator: lanes {r, r+16, r+32, r+48} hold row r partials
    denom += __shfl_xor(denom, 16, 64);
    denom += __shfl_xor(denom, 32, 64);
    if (lane < 16) dens[w][lane] = denom;

    // C-frag: col = lane&15, row = kg*4 + reg  (m89-verified layout)
    #pragma unroll
    for (int reg = 0; reg < 4; ++reg) {
        const int crow = kg * 4 + reg;
        accs[w][crow][ 0 + lane15] = A0[reg];
        accs[w][crow][16 + lane15] = A1[reg];
        accs[w][crow][32 + lane15] = A2[reg];
        accs[w][crow][48 + lane15] = A3[reg];
    }
    __syncthreads();

    // combine the 4 m-quarters and normalize
    const int col = tid & 63;
    const int rq  = tid >> 6;
    #pragma unroll
    for (int i = 0; i < 4; ++i) {
        const int r = rq * 4 + i;
        float s = (accs[0][r][col] + accs[1][r][col])
                + (accs[2][r][col] + accs[3][r][col]);
        float d = (dens[0][r] + dens[1][r]) + (dens[2][r] + dens[3][r]);
        out[((size_t)b * N + n0 + r) * FOUT + col] = s / d;
    }
}

extern "C" void kernel_launch(void* const* d_in, const int* in_sizes, int n_in,
                              void* d_out, int out_size, void* d_ws, size_t ws_size,
                              hipStream_t stream) {
    const float* h   = (const float*)d_in[0];
    const float* adj = (const float*)d_in[1];
    const float* W   = (const float*)d_in[2];
    const float* bv  = (const float*)d_in[3];
    const float* a_w = (const float*)d_in[4];
    const float* a_b = (const float*)d_in[5];
    float* out = (float*)d_out;

    float* e1 = (float*)d_ws;                    // B*N floats
    float* E1 = e1 + (size_t)B * N;              // B*N
    float* E2 = E1 + (size_t)B * N;              // B*N
    unsigned short* Whb = (unsigned short*)(E2 + (size_t)B * N);   // 2 MB bf16 frags

    wh_kernel<<<B * N / 16, 256, 0, stream>>>(h, W, bv, a_w, a_b, e1, E1, E2, Whb);
    attn_mfma<<<B * N / 16, 256, 0, stream>>>(adj, Whb, e1, E1, E2, out);
}

// Round 14
// 50.260 us; speedup vs baseline: 1.3125x; 1.0424x over previous
//
#include <hip/hip_runtime.h>
#include <hip/hip_bf16.h>

// GraphAttentionLayer: bs=8, N=2048, Fin=128, Fout=64, fp32.
// h_prime[b,n,:] = sum_m softmax_m(LeakyReLU(e1[n]+e2[m]+ab)) * adj[b,n,m] * Wh[b,m,:]
// Identity: exp(LeakyReLU(y)) = max(exp(y), exp(0.1*y))
//   => pa[n,m] = max(c1[n]*E1[m], c2[n]*E2[m]).
// R14 = R13 + LDS union (40KB, 4 blocks/CU) + adj L2/L3 pre-warm in wh tail.

#define ALPHA 0.1f
constexpr int B    = 8;
constexpr int N    = 2048;
constexpr int FIN  = 128;
constexpr int FOUT = 64;

typedef __bf16 bf16x8 __attribute__((ext_vector_type(8)));
typedef float  f32x4  __attribute__((ext_vector_type(4)));

// ---------------- Kernel 1: GEMM + side outputs + fused pack + pre-warm ----
// LDS = Wl4 (32KB) + hl (8KB, reused as sAcc after the GEMM) = 40 KB exactly
// -> 4 blocks/CU, 1024 blocks in one generation.
__global__ __launch_bounds__(256) void wh_kernel(
    const float* __restrict__ h, const float* __restrict__ W,
    const float* __restrict__ bias, const float* __restrict__ a_w,
    const float* __restrict__ a_b, const float* __restrict__ adj,
    float* __restrict__ e1, float* __restrict__ E1, float* __restrict__ E2,
    unsigned short* __restrict__ Whb)
{
    __shared__ __align__(16) float Wl4[FIN * FOUT];   // 32 KB, packed (k4,o,kj)
    __shared__ __align__(16) float hl[16 * FIN];      // 8 KB; reused as sAcc[16][64]

    const int tid = threadIdx.x;
    const int blk = blockIdx.x;           // 0..1023
    const int b   = blk >> 7;
    const int n0  = (blk & 127) * 16;

    for (int i = tid; i < FIN * FOUT / 4; i += 256) {
        float4 wv = ((const float4*)W)[i];     // W[k][o4..o4+3]
        int k  = i >> 4;
        int o4 = (i & 15) * 4;
        int k4 = k >> 2, kj = k & 3;
        Wl4[(k4 * 64 + o4 + 0) * 4 + kj] = wv.x;
        Wl4[(k4 * 64 + o4 + 1) * 4 + kj] = wv.y;
        Wl4[(k4 * 64 + o4 + 2) * 4 + kj] = wv.z;
        Wl4[(k4 * 64 + o4 + 3) * 4 + kj] = wv.w;
    }
    const float* hb = h + (size_t)(b * N + n0) * FIN;
    for (int i = tid; i < 16 * FIN / 4; i += 256)
        ((float4*)hl)[i] = ((const float4*)hb)[i];
    __syncthreads();

    const int w  = tid >> 6;
    const int o  = tid & 63;
    const int r0 = w * 4;

    float acc[4];
    float bo_ = bias[o];
    #pragma unroll
    for (int rr = 0; rr < 4; ++rr) acc[rr] = bo_;

    #pragma unroll 8
    for (int k4 = 0; k4 < FIN / 4; ++k4) {
        float4 wv = ((const float4*)Wl4)[k4 * 64 + o];
        #pragma unroll
        for (int rr = 0; rr < 4; ++rr) {
            float4 hv = ((const float4*)hl)[(r0 + rr) * 32 + k4];
            acc[rr] = fmaf(hv.x, wv.x, acc[rr]);
            acc[rr] = fmaf(hv.y, wv.y, acc[rr]);
            acc[rr] = fmaf(hv.z, wv.z, acc[rr]);
            acc[rr] = fmaf(hv.w, wv.w, acc[rr]);
        }
    }
    __syncthreads();                       // all waves done READING hl

    // sAcc aliases hl storage (4 KB of the 8 KB)
    float* sAcc = hl;
    const float a1 = a_w[o], a2 = a_w[FOUT + o];
    const float ab = a_b[0];
    #pragma unroll
    for (int rr = 0; rr < 4; ++rr) {
        const int n = n0 + r0 + rr;
        sAcc[(r0 + rr) * 64 + o] = acc[rr];
        float v1 = acc[rr] * a1;
        float v2 = acc[rr] * a2;
        #pragma unroll
        for (int off = 32; off > 0; off >>= 1) {
            v1 += __shfl_xor(v1, off, 64);
            v2 += __shfl_xor(v2, off, 64);
        }
        if (o == 0) {
            e1[b * N + n] = v1 + ab;          // rowbase, a_b folded in
            E1[b * N + n] = __expf(v2);
            E2[b * N + n] = __expf(ALPHA * v2);
        }
    }
    __syncthreads();

    // ---- fused pack: sAcc -> bf16 B-fragment units ------------------------
    if (tid < 128) {
        const int ct  = tid >> 5;         // 0..3 col-tile
        const int kgl = (tid >> 4) & 1;   // 0..1 local k-group
        const int col = tid & 15;
        const int mc      = n0 >> 5;
        const int kg_base = (n0 & 16) ? 2 : 0;
        const int kg      = kg_base + kgl;

        unsigned short us[8];
        #pragma unroll
        for (int j = 0; j < 8; ++j) {
            unsigned int u = __float_as_uint(sAcc[(kgl * 8 + j) * 64 + ct * 16 + col]);
            u += 0x7FFFu + ((u >> 16) & 1u);           // RNE to bf16
            us[j] = (unsigned short)(u >> 16);
        }
        int4 pk;
        pk.x = (int)(us[0] | ((unsigned)us[1] << 16));
        pk.y = (int)(us[2] | ((unsigned)us[3] << 16));
        pk.z = (int)(us[4] | ((unsigned)us[5] << 16));
        pk.w = (int)(us[6] | ((unsigned)us[7] << 16));
        ((int4*)Whb)[(((size_t)b * 64 + mc) * 4 + ct) * 64 + kg * 16 + col] = pk;
    }

    // ---- adj pre-warm: first 2 t-steps of this tile's rows (16 KB) --------
    // Warms L2/L3 for the attn block that maps to the same (b, n0); loads
    // kept live via empty asm (rule #17), no stores.
    {
        const float4* adjw = (const float4*)(adj + ((size_t)b * N + n0) * N);
        float keep = 0.f;
        #pragma unroll
        for (int it = 0; it < 4; ++it) {
            int idx = it * 256 + tid;        // 0..1023
            int row = idx >> 6;              // 0..15
            int wq  = (idx >> 4) & 3;        // m-quarter
            int sg  = idx & 15;              // 16B segment -> floats 0..63 (t=0,1)
            float4 v = adjw[(size_t)row * (N / 4) + wq * 128 + sg];
            keep += (v.x + v.y) + (v.z + v.w);
        }
        asm volatile("" :: "v"(keep));
    }
}

// ---------------- Kernel 2: dense attention via MFMA -----------------------
struct Frag {
    float4 a0, a1;
    float4 x0, x1, y0, y1;
    bf16x8 b0, b1, b2, b3;
};

__device__ __forceinline__ void load_step(
    Frag& f, const float* adjr, const float* E1b, const float* E2b,
    const bf16x8* BfragB, int w, int t, int kg, int lane)
{
    const int mo = w * 512 + t * 32 + kg * 8;
    f.a0 = *(const float4*)(adjr + mo);
    f.a1 = *(const float4*)(adjr + mo + 4);
    f.x0 = *(const float4*)(E1b + mo);
    f.x1 = *(const float4*)(E1b + mo + 4);
    f.y0 = *(const float4*)(E2b + mo);
    f.y1 = *(const float4*)(E2b + mo + 4);
    const bf16x8* bp = BfragB + (size_t)(w * 16 + t) * 256 + lane;
    f.b0 = bp[0];
    f.b1 = bp[64];
    f.b2 = bp[128];
    f.b3 = bp[192];
}

__device__ __forceinline__ void compute_step(
    const Frag& f, float c1, float c2, float& denom,
    f32x4& A0, f32x4& A1, f32x4& A2, f32x4& A3)
{
    float p[8], q[8];
    p[0] = fmaxf(c1 * f.x0.x, c2 * f.y0.x); q[0] = p[0] * f.a0.x;
    p[1] = fmaxf(c1 * f.x0.y, c2 * f.y0.y); q[1] = p[1] * f.a0.y;
    p[2] = fmaxf(c1 * f.x0.z, c2 * f.y0.z); q[2] = p[2] * f.a0.z;
    p[3] = fmaxf(c1 * f.x0.w, c2 * f.y0.w); q[3] = p[3] * f.a0.w;
    p[4] = fmaxf(c1 * f.x1.x, c2 * f.y1.x); q[4] = p[4] * f.a1.x;
    p[5] = fmaxf(c1 * f.x1.y, c2 * f.y1.y); q[5] = p[5] * f.a1.y;
    p[6] = fmaxf(c1 * f.x1.z, c2 * f.y1.z); q[6] = p[6] * f.a1.z;
    p[7] = fmaxf(c1 * f.x1.w, c2 * f.y1.w); q[7] = p[7] * f.a1.w;
    denom += ((p[0] + p[1]) + (p[2] + p[3])) + ((p[4] + p[5]) + (p[6] + p[7]));

    bf16x8 af;
    af[0] = (__bf16)q[0]; af[1] = (__bf16)q[1];
    af[2] = (__bf16)q[2]; af[3] = (__bf16)q[3];
    af[4] = (__bf16)q[4]; af[5] = (__bf16)q[5];
    af[6] = (__bf16)q[6]; af[7] = (__bf16)q[7];

    A0 = __builtin_amdgcn_mfma_f32_16x16x32_bf16(af, f.b0, A0, 0, 0, 0);
    A1 = __builtin_amdgcn_mfma_f32_16x16x32_bf16(af, f.b1, A1, 0, 0, 0);
    A2 = __builtin_amdgcn_mfma_f32_16x16x32_bf16(af, f.b2, A2, 0, 0, 0);
    A3 = __builtin_amdgcn_mfma_f32_16x16x32_bf16(af, f.b3, A3, 0, 0, 0);
}

__global__ __launch_bounds__(256) void attn_mfma(
    const float* __restrict__ adj, const unsigned short* __restrict__ Whb,
    const float* __restrict__ e1, const float* __restrict__ E1,
    const float* __restrict__ E2, float* __restrict__ out)
{
    __shared__ float accs[4][16][66];   // [wave][crow][col], stride 66 anti-conflict
    __shared__ float dens[4][16];

    const int tid  = threadIdx.x;
    int blkr = blockIdx.x;
    const int blk = (blkr & 7) * 128 + (blkr >> 3);   // XCD swizzle: one batch/XCD
    const int b   = blk >> 7;
    const int n0  = (blk & 127) * 16;

    const int w      = tid >> 6;
    const int lane   = tid & 63;
    const int lane15 = lane & 15;
    const int kg     = lane >> 4;

    const int n_row = n0 + lane15;      // this lane's A-operand row
    const float rowbase = e1[b * N + n_row];
    const float c1 = __expf(rowbase);
    const float c2 = __expf(ALPHA * rowbase);

    const float* adjr  = adj + ((size_t)b * N + n_row) * N;
    const float* E1b   = E1 + b * N;
    const float* E2b   = E2 + b * N;
    const bf16x8* BfragB = (const bf16x8*)Whb + (size_t)b * 64 * 256;

    f32x4 A0 = {0.f, 0.f, 0.f, 0.f}, A1 = A0, A2 = A0, A3 = A0;
    float denom = 0.f;

    Frag fc, fn;
    load_step(fc, adjr, E1b, E2b, BfragB, w, 0, kg, lane);
    #pragma unroll
    for (int t = 0; t < 16; ++t) {
        if (t < 15)
            load_step(fn, adjr, E1b, E2b, BfragB, w, t + 1, kg, lane);
        compute_step(fc, c1, c2, denom, A0, A1, A2, A3);
        if (t < 15)
            fc = fn;
    }

    // row-denominator: lanes {r, r+16, r+32, r+48} hold row r partials
    denom += __shfl_xor(denom, 16, 64);
    denom += __shfl_xor(denom, 32, 64);
    if (lane < 16) dens[w][lane] = denom;

    // C-frag: col = lane&15, row = kg*4 + reg  (m89-verified layout)
    #pragma unroll
    for (int reg = 0; reg < 4; ++reg) {
        const int crow = kg * 4 + reg;
        accs[w][crow][ 0 + lane15] = A0[reg];
        accs[w][crow][16 + lane15] = A1[reg];
        accs[w][crow][32 + lane15] = A2[reg];
        accs[w][crow][48 + lane15] = A3[reg];
    }
    __syncthreads();

    // combine the 4 m-quarters and normalize
    const int col = tid & 63;
    const int rq  = tid >> 6;
    #pragma unroll
    for (int i = 0; i < 4; ++i) {
        const int r = rq * 4 + i;
        float s = (accs[0][r][col] + accs[1][r][col])
                + (accs[2][r][col] + accs[3][r][col]);
        float d = (dens[0][r] + dens[1][r]) + (dens[2][r] + dens[3][r]);
        out[((size_t)b * N + n0 + r) * FOUT + col] = s / d;
    }
}

extern "C" void kernel_launch(void* const* d_in, const int* in_sizes, int n_in,
                              void* d_out, int out_size, void* d_ws, size_t ws_size,
                              hipStream_t stream) {
    const float* h   = (const float*)d_in[0];
    const float* adj = (const float*)d_in[1];
    const float* W   = (const float*)d_in[2];
    const float* bv  = (const float*)d_in[3];
    const float* a_w = (const float*)d_in[4];
    const float* a_b = (const float*)d_in[5];
    float* out = (float*)d_out;

    float* e1 = (float*)d_ws;                    // B*N floats
    float* E1 = e1 + (size_t)B * N;              // B*N
    float* E2 = E1 + (size_t)B * N;              // B*N
    unsigned short* Whb = (unsigned short*)(E2 + (size_t)B * N);   // 2 MB bf16 frags

    wh_kernel<<<B * N / 16, 256, 0, stream>>>(h, W, bv, a_w, a_b, adj,
                                              e1, E1, E2, Whb);
    attn_mfma<<<B * N / 16, 256, 0, stream>>>(adj, Whb, e1, E1, E2, out);
}